// Round 5
// baseline (235.755 us; speedup 1.0000x reference)
//
#include <hip/hip_runtime.h>
#include <math.h>

#define BH  16384   // half batch
#define B2  32768
#define DIM 256
#define KC  1024    // clusters

typedef __bf16 bf16x8 __attribute__((ext_vector_type(8)));
typedef float  f32x4  __attribute__((ext_vector_type(4)));

__device__ __forceinline__ unsigned short f2bf(float f) {
  unsigned int u = __float_as_uint(f);
  u += 0x7FFFu + ((u >> 16) & 1u);   // RNE; inputs are finite
  return (unsigned short)(u >> 16);
}

__device__ __forceinline__ float vsqrt(float x) {
  float r; asm("v_sqrt_f32 %0, %1" : "=v"(r) : "v"(x)); return r;
}

__device__ __forceinline__ float dist_L(float dotv) {
  // L = D/eps = 20*sqrt(max(2-2*dot, 1e-12))
  return 20.0f * vsqrt(fmaxf(2.0f - 2.0f * dotv, 1e-12f));
}

__device__ __forceinline__ void gld_lds16(const void* g, void* l) {
  __builtin_amdgcn_global_load_lds(
      (const __attribute__((address_space(1))) void*)g,
      (__attribute__((address_space(3))) void*)l, 16, 0, 0);
}

// one wave per row: l2-normalize and convert to bf16
__global__ void norm_rows_kernel(const float* __restrict__ z,
                                 const float* __restrict__ p,
                                 const float* __restrict__ c,
                                 unsigned short* __restrict__ Xn,
                                 unsigned short* __restrict__ Cn) {
  int wave = threadIdx.x >> 6;
  int lane = threadIdx.x & 63;
  int row  = blockIdx.x * 4 + wave;          // 0 .. 66559
  const float* src; unsigned short* dst; int r;
  if (row < B2)        { src = z; dst = Xn; r = row; }
  else if (row < 2*B2) { src = p; dst = Xn + (size_t)B2 * DIM; r = row - B2; }
  else                 { src = c; dst = Cn; r = row - 2*B2; }
  float4 v = *reinterpret_cast<const float4*>(src + (size_t)r * DIM + lane * 4);
  float ss = v.x*v.x + v.y*v.y + v.z*v.z + v.w*v.w;
  #pragma unroll
  for (int m = 1; m < 64; m <<= 1) ss += __shfl_xor(ss, m);
  float inv = 1.0f / fmaxf(vsqrt(ss), 1e-12f);
  ushort4 o;
  o.x = f2bf(v.x * inv); o.y = f2bf(v.y * inv);
  o.z = f2bf(v.z * inv); o.w = f2bf(v.w * inv);
  *reinterpret_cast<ushort4*>(dst + (size_t)r * DIM + lane * 4) = o;
}

__global__ void zero_kernel(float* __restrict__ colsum,
                            float* __restrict__ rowAux,
                            float* __restrict__ out) {
  int i = blockIdx.x * 256 + threadIdx.x;
  if (i < 6 * BH) rowAux[i] = 0.0f;
  if (i < 4 * KC) colsum[i] = 0.0f;
  if (i == 0)     out[0]    = 0.0f;
}

__global__ void fin_logC_kernel(const float* __restrict__ colsum,
                                float* __restrict__ logC) {
  int i = blockIdx.x * 256 + threadIdx.x;
  if (i < 4 * KC) logC[i] = 40.0f + __logf(colsum[i]);
}

// loss = -(1/4B) * sum_b [num_z1/den_z1 + num_z2/den_z2 - 2(log den_p1 + log den_p2)]
__global__ void fin_loss_kernel(const float* __restrict__ rowAux,
                                float* __restrict__ out) {
  int i = blockIdx.x * 256 + threadIdx.x;   // 64 blocks x 256 = BH
  const float* denP1 = rowAux;
  const float* denP2 = rowAux + BH;
  const float* denZ1 = rowAux + 2 * BH;
  const float* denZ2 = rowAux + 3 * BH;
  const float* numZ1 = rowAux + 4 * BH;
  const float* numZ2 = rowAux + 5 * BH;
  float v = numZ1[i] / denZ1[i] + numZ2[i] / denZ2[i]
          - 2.0f * (__logf(denP1[i]) + __logf(denP2[i]));
  #pragma unroll
  for (int m = 1; m < 64; m <<= 1) v += __shfl_xor(v, m);
  __shared__ float ws[4];
  int lane = threadIdx.x & 63, wid = threadIdx.x >> 6;
  if (lane == 0) ws[wid] = v;
  __syncthreads();
  if (threadIdx.x == 0)
    atomicAdd(out, (ws[0] + ws[1] + ws[2] + ws[3]) * (-1.0f / 65536.0f));
}

// Unified GEMM pass over a fixed 128x128 (rows x cols) tile, looping the
// 4 matrices in order p1,p2,z1,z2 (mat = (mi+2)&3).
// PASS 0: colsum[mat][k] += sum_b exp(L-40)
// PASS 2: mi<2: tv = G_p1+G_p2, denP += exp(G); mi>=2: denZ += exp(G),
//         numZ += exp(G)*tv   (all via rowAux atomics)
template<int PASS>
__global__ __launch_bounds__(256, 2)
void gemm_pass(const unsigned short* __restrict__ XA,  // [4][BH][DIM]
               const unsigned short* __restrict__ Cn,  // [KC][DIM]
               float* __restrict__ colsum,
               const float* __restrict__ logC,
               float* __restrict__ rowAux) {
  __shared__ __align__(16) char lds[65536];  // A: 2x16KB @0; B: 2x16KB @32768
  // XCD-chunked swizzle: all 8 col-blocks of a row-panel on one XCD
  const int id  = blockIdx.x;            // 1024
  const int xcd = id & 7, idx = id >> 3;
  const int wk  = xcd * 128 + idx;       // 1024 % 8 == 0 -> bijective
  const int panel = wk >> 3, col = wk & 7;
  const int tm0 = panel * 128, tn0 = col * 128;

  const int tid  = threadIdx.x;
  const int lane = tid & 63;
  const int wid  = tid >> 6;
  const int wm   = wid >> 1, wn = wid & 1;
  const int l15  = lane & 15, l4 = lane >> 4;

  int arow[4], acs[4];
  #pragma unroll
  for (int it = 0; it < 4; ++it) {
    int slot = it * 256 + tid;
    int r = slot >> 3, c = slot & 7;
    arow[it] = r;
    acs[it]  = c ^ (r & 7);    // pre-swizzled source chunk (involution)
  }
  const char* Abase = (const char*)XA + (size_t)tm0 * 512;
  const char* Bbase = (const char*)Cn + (size_t)tn0 * 512;

  auto stage = [&](int t) {
    const int mat = ((t >> 2) + 2) & 3;
    const int bk  = t & 3;
    const int b   = t & 1;
    const char* ab = Abase + ((size_t)mat << 23);   // mat * BH * 512
    #pragma unroll
    for (int it = 0; it < 4; ++it) {
      gld_lds16(ab + (size_t)arow[it] * 512 + bk * 128 + acs[it] * 16,
                lds + b * 16384 + (it * 256 + tid) * 16);
      gld_lds16(Bbase + (size_t)arow[it] * 512 + bk * 128 + acs[it] * 16,
                lds + 32768 + b * 16384 + (it * 256 + tid) * 16);
    }
  };

  f32x4 acc[4][4];
  float tv[4][4][4];   // PASS 2 only (dead in PASS 0 -> DCE)

  stage(0);

  #pragma unroll 1
  for (int t = 0; t < 16; ++t) {
    // T4 counted-vmcnt pipeline: keep next tile's 8 loads in flight across
    // both barriers; never drain to 0 mid-loop.
    if (t < 15) {
      stage(t + 1);
      asm volatile("s_waitcnt vmcnt(8)" ::: "memory");
    } else {
      asm volatile("s_waitcnt vmcnt(0)" ::: "memory");
    }
    __builtin_amdgcn_sched_barrier(0);
    __builtin_amdgcn_s_barrier();       // all waves' stage(t) complete
    __builtin_amdgcn_sched_barrier(0);

    const int b  = t & 1;
    const int mi = t >> 2, bk = t & 3;
    const int mat = (mi + 2) & 3;

    if (bk == 0) {
      #pragma unroll
      for (int fi = 0; fi < 4; ++fi)
        #pragma unroll
        for (int fj = 0; fj < 4; ++fj)
          acc[fi][fj] = (f32x4){0.f, 0.f, 0.f, 0.f};
    }

    #pragma unroll
    for (int kc = 0; kc < 2; ++kc) {
      bf16x8 aF[4], bF[4];
      #pragma unroll
      for (int f = 0; f < 4; ++f) {
        const int ra = wm * 64 + f * 16 + l15;
        aF[f] = *reinterpret_cast<const bf16x8*>(
            lds + b * 16384 + ra * 128 + ((((kc << 2) | l4) ^ (ra & 7)) << 4));
        const int rb = wn * 64 + f * 16 + l15;
        bF[f] = *reinterpret_cast<const bf16x8*>(
            lds + 32768 + b * 16384 + rb * 128 + ((((kc << 2) | l4) ^ (rb & 7)) << 4));
      }
      #pragma unroll
      for (int fi = 0; fi < 4; ++fi)
        #pragma unroll
        for (int fj = 0; fj < 4; ++fj)
          acc[fi][fj] = __builtin_amdgcn_mfma_f32_16x16x32_bf16(
              aF[fi], bF[fj], acc[fi][fj], 0, 0, 0);
    }

    if (bk == 3) {
      if (PASS == 0) {
        #pragma unroll
        for (int fj = 0; fj < 4; ++fj) {
          float cp = 0.0f;
          #pragma unroll
          for (int fi = 0; fi < 4; ++fi)
            #pragma unroll
            for (int i = 0; i < 4; ++i)
              cp += __expf(dist_L(acc[fi][fj][i]) - 40.0f);
          cp += __shfl_xor(cp, 16);
          cp += __shfl_xor(cp, 32);
          if (l4 == 0)
            atomicAdd(&colsum[mat * KC + tn0 + wn * 64 + fj * 16 + l15], cp);
        }
      } else {
        float lc[4];
        #pragma unroll
        for (int fj = 0; fj < 4; ++fj)
          lc[fj] = logC[mat * KC + tn0 + wn * 64 + fj * 16 + l15];

        if (mi < 2) {           // p1 / p2: build tv, accumulate den_p
          float rp[4][4];
          #pragma unroll
          for (int fi = 0; fi < 4; ++fi)
            #pragma unroll
            for (int i = 0; i < 4; ++i) rp[fi][i] = 0.0f;
          #pragma unroll
          for (int fi = 0; fi < 4; ++fi)
            #pragma unroll
            for (int fj = 0; fj < 4; ++fj)
              #pragma unroll
              for (int i = 0; i < 4; ++i) {
                float G = dist_L(acc[fi][fj][i]) - lc[fj];
                tv[fi][fj][i] = (mi == 0) ? G : (tv[fi][fj][i] + G);
                rp[fi][i] += __expf(G);
              }
          float* denP = rowAux + (size_t)mi * BH;
          #pragma unroll
          for (int fi = 0; fi < 4; ++fi)
            #pragma unroll
            for (int i = 0; i < 4; ++i) {
              float v = rp[fi][i];
              v += __shfl_xor(v, 1); v += __shfl_xor(v, 2);
              v += __shfl_xor(v, 4); v += __shfl_xor(v, 8);
              if (l15 == 0)
                atomicAdd(&denP[tm0 + wm * 64 + fi * 16 + l4 * 4 + i], v);
            }
        } else {                // z1 / z2: accumulate den_z and num_z
          float rd[4][4], rn[4][4];
          #pragma unroll
          for (int fi = 0; fi < 4; ++fi)
            #pragma unroll
            for (int i = 0; i < 4; ++i) { rd[fi][i] = 0.0f; rn[fi][i] = 0.0f; }
          #pragma unroll
          for (int fi = 0; fi < 4; ++fi)
            #pragma unroll
            for (int fj = 0; fj < 4; ++fj)
              #pragma unroll
              for (int i = 0; i < 4; ++i) {
                float G = dist_L(acc[fi][fj][i]) - lc[fj];
                float e = __expf(G);
                rd[fi][i] += e;
                rn[fi][i] += e * tv[fi][fj][i];
              }
          float* denZ = rowAux + (size_t)mi * BH;        // mi=2,3 -> denZ1,denZ2
          float* numZ = rowAux + (size_t)(mi + 2) * BH;  //        -> numZ1,numZ2
          #pragma unroll
          for (int fi = 0; fi < 4; ++fi)
            #pragma unroll
            for (int i = 0; i < 4; ++i) {
              float vd = rd[fi][i], vn = rn[fi][i];
              vd += __shfl_xor(vd, 1); vd += __shfl_xor(vd, 2);
              vd += __shfl_xor(vd, 4); vd += __shfl_xor(vd, 8);
              vn += __shfl_xor(vn, 1); vn += __shfl_xor(vn, 2);
              vn += __shfl_xor(vn, 4); vn += __shfl_xor(vn, 8);
              if (l15 == 0) {
                int row = tm0 + wm * 64 + fi * 16 + l4 * 4 + i;
                atomicAdd(&denZ[row], vd);
                atomicAdd(&numZ[row], vn);
              }
            }
        }
      }
    }
    __builtin_amdgcn_s_barrier();       // reads of buf b done before overwrite
  }
}

extern "C" void kernel_launch(void* const* d_in, const int* in_sizes, int n_in,
                              void* d_out, int out_size, void* d_ws, size_t ws_size,
                              hipStream_t stream) {
  const float* z = (const float*)d_in[0];
  const float* p = (const float*)d_in[1];
  const float* c = (const float*)d_in[2];
  char* ws = (char*)d_ws;
  // layout: XA = [z1,z2,p1,p2] bf16 (33.55MB) | Cn 0.5MB | colsum | logC | rowAux
  unsigned short* Xn = (unsigned short*)(ws);
  unsigned short* Cn = (unsigned short*)(ws + 33554432);
  float* colsum = (float*)(ws + 34078720);
  float* logC   = (float*)(ws + 34095104);
  float* rowAux = (float*)(ws + 34111488);   // 6 * BH floats
  float* out = (float*)d_out;

  norm_rows_kernel<<<16640, 256, 0, stream>>>(z, p, c, Xn, Cn);
  zero_kernel<<<384, 256, 0, stream>>>(colsum, rowAux, out);

  gemm_pass<0><<<1024, 256, 0, stream>>>(Xn, Cn, colsum, logC, rowAux);
  fin_logC_kernel<<<16, 256, 0, stream>>>(colsum, logC);
  gemm_pass<2><<<1024, 256, 0, stream>>>(Xn, Cn, colsum, logC, rowAux);
  fin_loss_kernel<<<64, 256, 0, stream>>>(rowAux, out);
}

// Round 6
// 160.213 us; speedup vs baseline: 1.4715x; 1.4715x over previous
//
#include <hip/hip_runtime.h>
#include <math.h>

#define BH  16384   // half batch
#define B2  32768
#define DIM 256
#define KC  1024    // clusters

typedef __bf16 bf16x8 __attribute__((ext_vector_type(8)));
typedef float  f32x4  __attribute__((ext_vector_type(4)));

__device__ __forceinline__ unsigned short f2bf(float f) {
  unsigned int u = __float_as_uint(f);
  u += 0x7FFFu + ((u >> 16) & 1u);   // RNE; inputs are finite
  return (unsigned short)(u >> 16);
}

__device__ __forceinline__ float vsqrt(float x) {
  float r; asm("v_sqrt_f32 %0, %1" : "=v"(r) : "v"(x)); return r;
}

__device__ __forceinline__ float dist_L(float dotv) {
  // L = D/eps = 20*sqrt(max(2-2*dot, 1e-12))
  return 20.0f * vsqrt(fmaxf(2.0f - 2.0f * dotv, 1e-12f));
}

__device__ __forceinline__ unsigned pk2(float lo, float hi) {
  unsigned r;
  asm("v_cvt_pk_bf16_f32 %0, %1, %2" : "=v"(r) : "v"(lo), "v"(hi));
  return r;
}
__device__ __forceinline__ float upk_lo(unsigned u) {
  return __uint_as_float(u << 16);
}
__device__ __forceinline__ float upk_hi(unsigned u) {
  return __uint_as_float(u & 0xffff0000u);
}

__device__ __forceinline__ void gld_lds16(const void* g, void* l) {
  __builtin_amdgcn_global_load_lds(
      (const __attribute__((address_space(1))) void*)g,
      (__attribute__((address_space(3))) void*)l, 16, 0, 0);
}

// one wave per row: l2-normalize and convert to bf16
__global__ void norm_rows_kernel(const float* __restrict__ z,
                                 const float* __restrict__ p,
                                 const float* __restrict__ c,
                                 unsigned short* __restrict__ Xn,
                                 unsigned short* __restrict__ Cn) {
  int wave = threadIdx.x >> 6;
  int lane = threadIdx.x & 63;
  int row  = blockIdx.x * 4 + wave;          // 0 .. 66559
  const float* src; unsigned short* dst; int r;
  if (row < B2)        { src = z; dst = Xn; r = row; }
  else if (row < 2*B2) { src = p; dst = Xn + (size_t)B2 * DIM; r = row - B2; }
  else                 { src = c; dst = Cn; r = row - 2*B2; }
  float4 v = *reinterpret_cast<const float4*>(src + (size_t)r * DIM + lane * 4);
  float ss = v.x*v.x + v.y*v.y + v.z*v.z + v.w*v.w;
  #pragma unroll
  for (int m = 1; m < 64; m <<= 1) ss += __shfl_xor(ss, m);
  float inv = 1.0f / fmaxf(vsqrt(ss), 1e-12f);
  ushort4 o;
  o.x = f2bf(v.x * inv); o.y = f2bf(v.y * inv);
  o.z = f2bf(v.z * inv); o.w = f2bf(v.w * inv);
  *reinterpret_cast<ushort4*>(dst + (size_t)r * DIM + lane * 4) = o;
}

__global__ void zero_kernel(float* __restrict__ colsum,
                            float* __restrict__ rowAux,
                            float* __restrict__ out) {
  int i = blockIdx.x * 256 + threadIdx.x;
  if (i < 6 * BH) rowAux[i] = 0.0f;
  if (i < 4 * KC) colsum[i] = 0.0f;
  if (i == 0)     out[0]    = 0.0f;
}

__global__ void fin_logC_kernel(const float* __restrict__ colsum,
                                float* __restrict__ logC) {
  int i = blockIdx.x * 256 + threadIdx.x;
  if (i < 4 * KC) logC[i] = 40.0f + __logf(colsum[i]);
}

// loss = -(1/4B) * sum_b [num_z1/den_z1 + num_z2/den_z2 - 2(log den_p1 + log den_p2)]
__global__ void fin_loss_kernel(const float* __restrict__ rowAux,
                                float* __restrict__ out) {
  int i = blockIdx.x * 256 + threadIdx.x;   // 64 blocks x 256 = BH
  const float* denP1 = rowAux;
  const float* denP2 = rowAux + BH;
  const float* denZ1 = rowAux + 2 * BH;
  const float* denZ2 = rowAux + 3 * BH;
  const float* numZ1 = rowAux + 4 * BH;
  const float* numZ2 = rowAux + 5 * BH;
  float v = numZ1[i] / denZ1[i] + numZ2[i] / denZ2[i]
          - 2.0f * (__logf(denP1[i]) + __logf(denP2[i]));
  #pragma unroll
  for (int m = 1; m < 64; m <<= 1) v += __shfl_xor(v, m);
  __shared__ float ws[4];
  int lane = threadIdx.x & 63, wid = threadIdx.x >> 6;
  if (lane == 0) ws[wid] = v;
  __syncthreads();
  if (threadIdx.x == 0)
    atomicAdd(out, (ws[0] + ws[1] + ws[2] + ws[3]) * (-1.0f / 65536.0f));
}

// Unified GEMM pass over a fixed 128x128 (rows x cols) tile, looping the
// 4 matrices in order p1,p2,z1,z2 (mat = (mi+2)&3).
// PASS 0: colsum[mat][k] += sum_b exp(L-40)
// PASS 2: mi<2: tvp = pack_bf16(G_p1+G_p2), denP += exp(G);
//         mi>=2: denZ += exp(G), numZ += exp(G)*tv   (rowAux atomics)
template<int PASS>
__global__ __launch_bounds__(256, 2)
void gemm_pass(const unsigned short* __restrict__ XA,  // [4][BH][DIM]
               const unsigned short* __restrict__ Cn,  // [KC][DIM]
               float* __restrict__ colsum,
               const float* __restrict__ logC,
               float* __restrict__ rowAux) {
  __shared__ __align__(16) char lds[65536];  // A: 2x16KB @0; B: 2x16KB @32768
  // XCD-chunked swizzle: all 8 col-blocks of a row-panel on one XCD
  const int id  = blockIdx.x;            // 1024
  const int xcd = id & 7, idx = id >> 3;
  const int wk  = xcd * 128 + idx;       // 1024 % 8 == 0 -> bijective
  const int panel = wk >> 3, col = wk & 7;
  const int tm0 = panel * 128, tn0 = col * 128;

  const int tid  = threadIdx.x;
  const int lane = tid & 63;
  const int wid  = tid >> 6;
  const int wm   = wid >> 1, wn = wid & 1;
  const int l15  = lane & 15, l4 = lane >> 4;

  int arow[4], acs[4];
  #pragma unroll
  for (int it = 0; it < 4; ++it) {
    int slot = it * 256 + tid;
    int r = slot >> 3, c = slot & 7;
    arow[it] = r;
    acs[it]  = c ^ (r & 7);    // pre-swizzled source chunk (involution)
  }
  const char* Abase = (const char*)XA + (size_t)tm0 * 512;
  const char* Bbase = (const char*)Cn + (size_t)tn0 * 512;

  auto stage = [&](int t) {
    const int mat = ((t >> 2) + 2) & 3;
    const int bk  = t & 3;
    const int b   = t & 1;
    const char* ab = Abase + ((size_t)mat << 23);   // mat * BH * 512
    #pragma unroll
    for (int it = 0; it < 4; ++it) {
      gld_lds16(ab + (size_t)arow[it] * 512 + bk * 128 + acs[it] * 16,
                lds + b * 16384 + (it * 256 + tid) * 16);
      gld_lds16(Bbase + (size_t)arow[it] * 512 + bk * 128 + acs[it] * 16,
                lds + 32768 + b * 16384 + (it * 256 + tid) * 16);
    }
  };

  f32x4 acc[4][4];
  unsigned tvp[4][4][2];   // PASS 2: G_p1+G_p2, bf16-packed (32 VGPR)

  stage(0);
  __syncthreads();

  for (int t = 0; t < 16; ++t) {
    if (t < 15) stage(t + 1);
    const int b  = t & 1;
    const int mi = t >> 2, bk = t & 3;
    const int mat = (mi + 2) & 3;

    if (bk == 0) {
      #pragma unroll
      for (int fi = 0; fi < 4; ++fi)
        #pragma unroll
        for (int fj = 0; fj < 4; ++fj)
          acc[fi][fj] = (f32x4){0.f, 0.f, 0.f, 0.f};
    }

    #pragma unroll
    for (int kc = 0; kc < 2; ++kc) {
      bf16x8 aF[4], bF[4];
      #pragma unroll
      for (int f = 0; f < 4; ++f) {
        const int ra = wm * 64 + f * 16 + l15;
        aF[f] = *reinterpret_cast<const bf16x8*>(
            lds + b * 16384 + ra * 128 + ((((kc << 2) | l4) ^ (ra & 7)) << 4));
        const int rb = wn * 64 + f * 16 + l15;
        bF[f] = *reinterpret_cast<const bf16x8*>(
            lds + 32768 + b * 16384 + rb * 128 + ((((kc << 2) | l4) ^ (rb & 7)) << 4));
      }
      #pragma unroll
      for (int fi = 0; fi < 4; ++fi)
        #pragma unroll
        for (int fj = 0; fj < 4; ++fj)
          acc[fi][fj] = __builtin_amdgcn_mfma_f32_16x16x32_bf16(
              aF[fi], bF[fj], acc[fi][fj], 0, 0, 0);
    }

    if (bk == 3) {
      if (PASS == 0) {
        #pragma unroll
        for (int fj = 0; fj < 4; ++fj) {
          float cp = 0.0f;
          #pragma unroll
          for (int fi = 0; fi < 4; ++fi)
            #pragma unroll
            for (int i = 0; i < 4; ++i)
              cp += __expf(dist_L(acc[fi][fj][i]) - 40.0f);
          cp += __shfl_xor(cp, 16);
          cp += __shfl_xor(cp, 32);
          if (l4 == 0)
            atomicAdd(&colsum[mat * KC + tn0 + wn * 64 + fj * 16 + l15], cp);
        }
      } else {
        float lc[4];
        #pragma unroll
        for (int fj = 0; fj < 4; ++fj)
          lc[fj] = logC[mat * KC + tn0 + wn * 64 + fj * 16 + l15];

        if (mi < 2) {           // p1 / p2: build packed tv, accumulate den_p
          float* denP = rowAux + (size_t)mi * BH;
          #pragma unroll
          for (int fi = 0; fi < 4; ++fi) {
            float rp[4] = {0.f, 0.f, 0.f, 0.f};
            #pragma unroll
            for (int fj = 0; fj < 4; ++fj) {
              float G[4];
              #pragma unroll
              for (int i = 0; i < 4; ++i) {
                G[i] = dist_L(acc[fi][fj][i]) - lc[fj];
                rp[i] += __expf(G[i]);
              }
              if (mi == 0) {
                tvp[fi][fj][0] = pk2(G[0], G[1]);
                tvp[fi][fj][1] = pk2(G[2], G[3]);
              } else {
                unsigned o0 = tvp[fi][fj][0], o1 = tvp[fi][fj][1];
                tvp[fi][fj][0] = pk2(upk_lo(o0) + G[0], upk_hi(o0) + G[1]);
                tvp[fi][fj][1] = pk2(upk_lo(o1) + G[2], upk_hi(o1) + G[3]);
              }
            }
            #pragma unroll
            for (int i = 0; i < 4; ++i) {
              float v = rp[i];
              v += __shfl_xor(v, 1); v += __shfl_xor(v, 2);
              v += __shfl_xor(v, 4); v += __shfl_xor(v, 8);
              if (l15 == 0)
                atomicAdd(&denP[tm0 + wm * 64 + fi * 16 + l4 * 4 + i], v);
            }
          }
        } else {                // z1 / z2: accumulate den_z and num_z
          float* denZ = rowAux + (size_t)mi * BH;        // mi=2,3 -> denZ1,denZ2
          float* numZ = rowAux + (size_t)(mi + 2) * BH;  //        -> numZ1,numZ2
          #pragma unroll
          for (int fi = 0; fi < 4; ++fi)
            #pragma unroll
            for (int i = 0; i < 4; ++i) {
              float rd = 0.f, rn = 0.f;
              #pragma unroll
              for (int fj = 0; fj < 4; ++fj) {
                float G = dist_L(acc[fi][fj][i]) - lc[fj];
                float e = __expf(G);
                unsigned u = tvp[fi][fj][i >> 1];
                float tvv = (i & 1) ? upk_hi(u) : upk_lo(u);
                rd += e;
                rn += e * tvv;
              }
              rd += __shfl_xor(rd, 1); rd += __shfl_xor(rd, 2);
              rd += __shfl_xor(rd, 4); rd += __shfl_xor(rd, 8);
              rn += __shfl_xor(rn, 1); rn += __shfl_xor(rn, 2);
              rn += __shfl_xor(rn, 4); rn += __shfl_xor(rn, 8);
              if (l15 == 0) {
                int row = tm0 + wm * 64 + fi * 16 + l4 * 4 + i;
                atomicAdd(&denZ[row], rd);
                atomicAdd(&numZ[row], rn);
              }
            }
        }
      }
    }
    __syncthreads();
  }
}

extern "C" void kernel_launch(void* const* d_in, const int* in_sizes, int n_in,
                              void* d_out, int out_size, void* d_ws, size_t ws_size,
                              hipStream_t stream) {
  const float* z = (const float*)d_in[0];
  const float* p = (const float*)d_in[1];
  const float* c = (const float*)d_in[2];
  char* ws = (char*)d_ws;
  // layout: XA = [z1,z2,p1,p2] bf16 (33.55MB) | Cn 0.5MB | colsum | logC | rowAux
  unsigned short* Xn = (unsigned short*)(ws);
  unsigned short* Cn = (unsigned short*)(ws + 33554432);
  float* colsum = (float*)(ws + 34078720);
  float* logC   = (float*)(ws + 34095104);
  float* rowAux = (float*)(ws + 34111488);   // 6 * BH floats
  float* out = (float*)d_out;

  norm_rows_kernel<<<16640, 256, 0, stream>>>(z, p, c, Xn, Cn);
  zero_kernel<<<384, 256, 0, stream>>>(colsum, rowAux, out);

  gemm_pass<0><<<1024, 256, 0, stream>>>(Xn, Cn, colsum, logC, rowAux);
  fin_logC_kernel<<<16, 256, 0, stream>>>(colsum, logC);
  gemm_pass<2><<<1024, 256, 0, stream>>>(Xn, Cn, colsum, logC, rowAux);
  fin_loss_kernel<<<64, 256, 0, stream>>>(rowAux, out);
}

// Round 7
// 116.342 us; speedup vs baseline: 2.0264x; 1.3771x over previous
//
#include <hip/hip_runtime.h>
#include <math.h>

#define BH  16384   // half batch
#define B2  32768
#define DIM 256
#define KC  1024    // clusters

typedef __bf16 bf16x8 __attribute__((ext_vector_type(8)));
typedef float  f32x4  __attribute__((ext_vector_type(4)));

#define S_SCL  1638.0f
#define S_INV  (1.0f / 1638.0f)

__device__ __forceinline__ unsigned short f2bf(float f) {
  unsigned int u = __float_as_uint(f);
  u += 0x7FFFu + ((u >> 16) & 1u);   // RNE; inputs are finite
  return (unsigned short)(u >> 16);
}

__device__ __forceinline__ float vsqrt(float x) {
  float r; asm("v_sqrt_f32 %0, %1" : "=v"(r) : "v"(x)); return r;
}

__device__ __forceinline__ float dist_L(float dotv) {
  // L = D/eps = 20*sqrt(max(2-2*dot, 1e-12))
  return 20.0f * vsqrt(fmaxf(2.0f - 2.0f * dotv, 1e-12f));
}

__device__ __forceinline__ unsigned pk2(float lo, float hi) {
  unsigned r;
  asm("v_cvt_pk_bf16_f32 %0, %1, %2" : "=v"(r) : "v"(lo), "v"(hi));
  return r;
}
__device__ __forceinline__ float upk_lo(unsigned u) {
  return __uint_as_float(u << 16);
}
__device__ __forceinline__ float upk_hi(unsigned u) {
  return __uint_as_float(u & 0xffff0000u);
}

__device__ __forceinline__ void gld_lds16(const void* g, void* l) {
  __builtin_amdgcn_global_load_lds(
      (const __attribute__((address_space(1))) void*)g,
      (__attribute__((address_space(3))) void*)l, 16, 0, 0);
}

// one wave per row: l2-normalize and convert to bf16
__global__ void norm_rows_kernel(const float* __restrict__ z,
                                 const float* __restrict__ p,
                                 const float* __restrict__ c,
                                 unsigned short* __restrict__ Xn,
                                 unsigned short* __restrict__ Cn) {
  int wave = threadIdx.x >> 6;
  int lane = threadIdx.x & 63;
  int row  = blockIdx.x * 4 + wave;          // 0 .. 66559
  const float* src; unsigned short* dst; int r;
  if (row < B2)        { src = z; dst = Xn; r = row; }
  else if (row < 2*B2) { src = p; dst = Xn + (size_t)B2 * DIM; r = row - B2; }
  else                 { src = c; dst = Cn; r = row - 2*B2; }
  float4 v = *reinterpret_cast<const float4*>(src + (size_t)r * DIM + lane * 4);
  float ss = v.x*v.x + v.y*v.y + v.z*v.z + v.w*v.w;
  #pragma unroll
  for (int m = 1; m < 64; m <<= 1) ss += __shfl_xor(ss, m);
  float inv = 1.0f / fmaxf(vsqrt(ss), 1e-12f);
  ushort4 o;
  o.x = f2bf(v.x * inv); o.y = f2bf(v.y * inv);
  o.z = f2bf(v.z * inv); o.w = f2bf(v.w * inv);
  *reinterpret_cast<ushort4*>(dst + (size_t)r * DIM + lane * 4) = o;
}

__global__ void zero_kernel(float* __restrict__ colsum,
                            float* __restrict__ rowAux,
                            float* __restrict__ out) {
  int i = blockIdx.x * 256 + threadIdx.x;
  if (i < 6 * BH) rowAux[i] = 0.0f;
  if (i < 4 * KC) colsum[i] = 0.0f;
  if (i == 0)     out[0]    = 0.0f;
}

__global__ void fin_logC_kernel(const float* __restrict__ colsum,
                                float* __restrict__ logC) {
  int i = blockIdx.x * 256 + threadIdx.x;
  if (i < 4 * KC) logC[i] = 40.0f + __logf(colsum[i]);
}

// ---------------- main path: GEMM once, store L as u16 -------------------

// gemm_s: colsum[mat][k] += sum_b exp(L-40)  AND  S[mat][b][k] = u16(L*1638)
__global__ __launch_bounds__(256, 2)
void gemm_s_kernel(const unsigned short* __restrict__ XA,  // [4][BH][DIM]
                   const unsigned short* __restrict__ Cn,  // [KC][DIM]
                   float* __restrict__ colsum,
                   unsigned short* __restrict__ S) {       // [4][BH][KC]
  __shared__ __align__(16) char lds[65536];  // A: 2x16KB @0; B: 2x16KB @32768
  const int id  = blockIdx.x;            // 1024
  const int xcd = id & 7, idx = id >> 3;
  const int wk  = xcd * 128 + idx;       // bijective (1024 % 8 == 0)
  const int panel = wk >> 3, col = wk & 7;
  const int tm0 = panel * 128, tn0 = col * 128;

  const int tid  = threadIdx.x;
  const int lane = tid & 63;
  const int wid  = tid >> 6;
  const int wm   = wid >> 1, wn = wid & 1;
  const int l15  = lane & 15, l4 = lane >> 4;

  int arow[4], acs[4];
  #pragma unroll
  for (int it = 0; it < 4; ++it) {
    int slot = it * 256 + tid;
    int r = slot >> 3, c = slot & 7;
    arow[it] = r;
    acs[it]  = c ^ (r & 7);    // pre-swizzled source chunk (involution)
  }
  const char* Abase = (const char*)XA + (size_t)tm0 * 512;
  const char* Bbase = (const char*)Cn + (size_t)tn0 * 512;

  auto stage = [&](int t) {
    const int mat = t >> 2;
    const int bk  = t & 3;
    const int b   = t & 1;
    const char* ab = Abase + ((size_t)mat << 23);   // mat * BH * 512
    #pragma unroll
    for (int it = 0; it < 4; ++it) {
      gld_lds16(ab + (size_t)arow[it] * 512 + bk * 128 + acs[it] * 16,
                lds + b * 16384 + (it * 256 + tid) * 16);
      gld_lds16(Bbase + (size_t)arow[it] * 512 + bk * 128 + acs[it] * 16,
                lds + 32768 + b * 16384 + (it * 256 + tid) * 16);
    }
  };

  f32x4 acc[4][4];
  stage(0);
  __syncthreads();

  for (int t = 0; t < 16; ++t) {
    if (t < 15) stage(t + 1);
    const int b  = t & 1;
    const int mat = t >> 2, bk = t & 3;

    if (bk == 0) {
      #pragma unroll
      for (int fi = 0; fi < 4; ++fi)
        #pragma unroll
        for (int fj = 0; fj < 4; ++fj)
          acc[fi][fj] = (f32x4){0.f, 0.f, 0.f, 0.f};
    }

    #pragma unroll
    for (int kc = 0; kc < 2; ++kc) {
      bf16x8 aF[4], bF[4];
      #pragma unroll
      for (int f = 0; f < 4; ++f) {
        const int ra = wm * 64 + f * 16 + l15;
        aF[f] = *reinterpret_cast<const bf16x8*>(
            lds + b * 16384 + ra * 128 + ((((kc << 2) | l4) ^ (ra & 7)) << 4));
        const int rb = wn * 64 + f * 16 + l15;
        bF[f] = *reinterpret_cast<const bf16x8*>(
            lds + 32768 + b * 16384 + rb * 128 + ((((kc << 2) | l4) ^ (rb & 7)) << 4));
      }
      #pragma unroll
      for (int fi = 0; fi < 4; ++fi)
        #pragma unroll
        for (int fj = 0; fj < 4; ++fj)
          acc[fi][fj] = __builtin_amdgcn_mfma_f32_16x16x32_bf16(
              aF[fi], bF[fj], acc[fi][fj], 0, 0, 0);
    }

    if (bk == 3) {
      unsigned short* Sp = S + ((size_t)mat * BH + tm0) * KC + tn0;
      #pragma unroll
      for (int fj = 0; fj < 4; ++fj) {
        float cp = 0.0f;
        #pragma unroll
        for (int fi = 0; fi < 4; ++fi)
          #pragma unroll
          for (int i = 0; i < 4; ++i) {
            float L = dist_L(acc[fi][fj][i]);
            cp += __expf(L - 40.0f);
            unsigned e = (unsigned)(L * S_SCL + 0.5f);
            int row = wm * 64 + fi * 16 + l4 * 4 + i;
            int ccol = wn * 64 + fj * 16 + l15;
            Sp[(size_t)row * KC + ccol] = (unsigned short)e;
          }
        cp += __shfl_xor(cp, 16);
        cp += __shfl_xor(cp, 32);
        if (l4 == 0)
          atomicAdd(&colsum[mat * KC + tn0 + wn * 64 + fj * 16 + l15], cp);
      }
    }
    __syncthreads();
  }
}

__device__ __forceinline__ float2 dec2(unsigned w, float lc0, float lc1) {
  float a = (float)(w & 0xffffu) * S_INV - lc0;
  float b = (float)(w >> 16)     * S_INV - lc1;
  return make_float2(a, b);
}

// one wave per row: stream 4 planes of S, compute per-row loss contribution
__global__ __launch_bounds__(256)
void pass2_mem_kernel(const unsigned short* __restrict__ S,
                      const float* __restrict__ logC,
                      float* __restrict__ rowv) {
  const int lane = threadIdx.x & 63;
  const int wid  = threadIdx.x >> 6;
  const int row  = blockIdx.x * 4 + wid;      // 4096 blocks -> BH rows
  const size_t plane = (size_t)BH * KC;
  const unsigned short* Sr = S + (size_t)row * KC;

  float dp1 = 0.f, dp2 = 0.f, dz1 = 0.f, dz2 = 0.f, nz1 = 0.f, nz2 = 0.f;

  #pragma unroll
  for (int it = 0; it < 2; ++it) {
    const int kb = it * 512 + lane * 8;
    uint4 vz1 = *reinterpret_cast<const uint4*>(Sr + 0 * plane + kb);
    uint4 vz2 = *reinterpret_cast<const uint4*>(Sr + 1 * plane + kb);
    uint4 vp1 = *reinterpret_cast<const uint4*>(Sr + 2 * plane + kb);
    uint4 vp2 = *reinterpret_cast<const uint4*>(Sr + 3 * plane + kb);

    float4 cz1a = *reinterpret_cast<const float4*>(logC + 0 * KC + kb);
    float4 cz1b = *reinterpret_cast<const float4*>(logC + 0 * KC + kb + 4);
    float4 cz2a = *reinterpret_cast<const float4*>(logC + 1 * KC + kb);
    float4 cz2b = *reinterpret_cast<const float4*>(logC + 1 * KC + kb + 4);
    float4 cp1a = *reinterpret_cast<const float4*>(logC + 2 * KC + kb);
    float4 cp1b = *reinterpret_cast<const float4*>(logC + 2 * KC + kb + 4);
    float4 cp2a = *reinterpret_cast<const float4*>(logC + 3 * KC + kb);
    float4 cp2b = *reinterpret_cast<const float4*>(logC + 3 * KC + kb + 4);

    float g1[8], g2[8], tv[8];
    float2 r0, r1;
    // p1
    r0 = dec2(vp1.x, cp1a.x, cp1a.y); g1[0] = r0.x; g1[1] = r0.y;
    r1 = dec2(vp1.y, cp1a.z, cp1a.w); g1[2] = r1.x; g1[3] = r1.y;
    r0 = dec2(vp1.z, cp1b.x, cp1b.y); g1[4] = r0.x; g1[5] = r0.y;
    r1 = dec2(vp1.w, cp1b.z, cp1b.w); g1[6] = r1.x; g1[7] = r1.y;
    // p2
    r0 = dec2(vp2.x, cp2a.x, cp2a.y); g2[0] = r0.x; g2[1] = r0.y;
    r1 = dec2(vp2.y, cp2a.z, cp2a.w); g2[2] = r1.x; g2[3] = r1.y;
    r0 = dec2(vp2.z, cp2b.x, cp2b.y); g2[4] = r0.x; g2[5] = r0.y;
    r1 = dec2(vp2.w, cp2b.z, cp2b.w); g2[6] = r1.x; g2[7] = r1.y;
    #pragma unroll
    for (int e = 0; e < 8; ++e) {
      dp1 += __expf(g1[e]);
      dp2 += __expf(g2[e]);
      tv[e] = g1[e] + g2[e];
    }
    // z1
    r0 = dec2(vz1.x, cz1a.x, cz1a.y); g1[0] = r0.x; g1[1] = r0.y;
    r1 = dec2(vz1.y, cz1a.z, cz1a.w); g1[2] = r1.x; g1[3] = r1.y;
    r0 = dec2(vz1.z, cz1b.x, cz1b.y); g1[4] = r0.x; g1[5] = r0.y;
    r1 = dec2(vz1.w, cz1b.z, cz1b.w); g1[6] = r1.x; g1[7] = r1.y;
    // z2
    r0 = dec2(vz2.x, cz2a.x, cz2a.y); g2[0] = r0.x; g2[1] = r0.y;
    r1 = dec2(vz2.y, cz2a.z, cz2a.w); g2[2] = r1.x; g2[3] = r1.y;
    r0 = dec2(vz2.z, cz2b.x, cz2b.y); g2[4] = r0.x; g2[5] = r0.y;
    r1 = dec2(vz2.w, cz2b.z, cz2b.w); g2[6] = r1.x; g2[7] = r1.y;
    #pragma unroll
    for (int e = 0; e < 8; ++e) {
      float e1 = __expf(g1[e]);
      float e2 = __expf(g2[e]);
      dz1 += e1; nz1 += e1 * tv[e];
      dz2 += e2; nz2 += e2 * tv[e];
    }
  }

  #pragma unroll
  for (int m = 1; m < 64; m <<= 1) {
    dp1 += __shfl_xor(dp1, m); dp2 += __shfl_xor(dp2, m);
    dz1 += __shfl_xor(dz1, m); dz2 += __shfl_xor(dz2, m);
    nz1 += __shfl_xor(nz1, m); nz2 += __shfl_xor(nz2, m);
  }
  if (lane == 0)
    rowv[row] = nz1 / dz1 + nz2 / dz2 - 2.0f * (__logf(dp1) + __logf(dp2));
}

__global__ void fin_reduce_kernel(const float* __restrict__ rowv,
                                  float* __restrict__ out) {
  int i = blockIdx.x * 256 + threadIdx.x;   // 64 blocks x 256 = BH
  float v = rowv[i];
  #pragma unroll
  for (int m = 1; m < 64; m <<= 1) v += __shfl_xor(v, m);
  __shared__ float ws[4];
  int lane = threadIdx.x & 63, wid = threadIdx.x >> 6;
  if (lane == 0) ws[wid] = v;
  __syncthreads();
  if (threadIdx.x == 0)
    atomicAdd(out, (ws[0] + ws[1] + ws[2] + ws[3]) * (-1.0f / 65536.0f));
}

// ---------------- fallback path (round-6, ws too small for S) ------------

__global__ void fin_loss_kernel(const float* __restrict__ rowAux,
                                float* __restrict__ out) {
  int i = blockIdx.x * 256 + threadIdx.x;   // 64 blocks x 256 = BH
  const float* denP1 = rowAux;
  const float* denP2 = rowAux + BH;
  const float* denZ1 = rowAux + 2 * BH;
  const float* denZ2 = rowAux + 3 * BH;
  const float* numZ1 = rowAux + 4 * BH;
  const float* numZ2 = rowAux + 5 * BH;
  float v = numZ1[i] / denZ1[i] + numZ2[i] / denZ2[i]
          - 2.0f * (__logf(denP1[i]) + __logf(denP2[i]));
  #pragma unroll
  for (int m = 1; m < 64; m <<= 1) v += __shfl_xor(v, m);
  __shared__ float ws[4];
  int lane = threadIdx.x & 63, wid = threadIdx.x >> 6;
  if (lane == 0) ws[wid] = v;
  __syncthreads();
  if (threadIdx.x == 0)
    atomicAdd(out, (ws[0] + ws[1] + ws[2] + ws[3]) * (-1.0f / 65536.0f));
}

template<int PASS>
__global__ __launch_bounds__(256, 2)
void gemm_pass(const unsigned short* __restrict__ XA,
               const unsigned short* __restrict__ Cn,
               float* __restrict__ colsum,
               const float* __restrict__ logC,
               float* __restrict__ rowAux) {
  __shared__ __align__(16) char lds[65536];
  const int id  = blockIdx.x;
  const int xcd = id & 7, idx = id >> 3;
  const int wk  = xcd * 128 + idx;
  const int panel = wk >> 3, col = wk & 7;
  const int tm0 = panel * 128, tn0 = col * 128;

  const int tid  = threadIdx.x;
  const int lane = tid & 63;
  const int wid  = tid >> 6;
  const int wm   = wid >> 1, wn = wid & 1;
  const int l15  = lane & 15, l4 = lane >> 4;

  int arow[4], acs[4];
  #pragma unroll
  for (int it = 0; it < 4; ++it) {
    int slot = it * 256 + tid;
    int r = slot >> 3, c = slot & 7;
    arow[it] = r;
    acs[it]  = c ^ (r & 7);
  }
  const char* Abase = (const char*)XA + (size_t)tm0 * 512;
  const char* Bbase = (const char*)Cn + (size_t)tn0 * 512;

  auto stage = [&](int t) {
    const int mat = ((t >> 2) + 2) & 3;
    const int bk  = t & 3;
    const int b   = t & 1;
    const char* ab = Abase + ((size_t)mat << 23);
    #pragma unroll
    for (int it = 0; it < 4; ++it) {
      gld_lds16(ab + (size_t)arow[it] * 512 + bk * 128 + acs[it] * 16,
                lds + b * 16384 + (it * 256 + tid) * 16);
      gld_lds16(Bbase + (size_t)arow[it] * 512 + bk * 128 + acs[it] * 16,
                lds + 32768 + b * 16384 + (it * 256 + tid) * 16);
    }
  };

  f32x4 acc[4][4];
  unsigned tvp[4][4][2];

  stage(0);
  __syncthreads();

  for (int t = 0; t < 16; ++t) {
    if (t < 15) stage(t + 1);
    const int b  = t & 1;
    const int mi = t >> 2, bk = t & 3;
    const int mat = (mi + 2) & 3;

    if (bk == 0) {
      #pragma unroll
      for (int fi = 0; fi < 4; ++fi)
        #pragma unroll
        for (int fj = 0; fj < 4; ++fj)
          acc[fi][fj] = (f32x4){0.f, 0.f, 0.f, 0.f};
    }

    #pragma unroll
    for (int kc = 0; kc < 2; ++kc) {
      bf16x8 aF[4], bF[4];
      #pragma unroll
      for (int f = 0; f < 4; ++f) {
        const int ra = wm * 64 + f * 16 + l15;
        aF[f] = *reinterpret_cast<const bf16x8*>(
            lds + b * 16384 + ra * 128 + ((((kc << 2) | l4) ^ (ra & 7)) << 4));
        const int rb = wn * 64 + f * 16 + l15;
        bF[f] = *reinterpret_cast<const bf16x8*>(
            lds + 32768 + b * 16384 + rb * 128 + ((((kc << 2) | l4) ^ (rb & 7)) << 4));
      }
      #pragma unroll
      for (int fi = 0; fi < 4; ++fi)
        #pragma unroll
        for (int fj = 0; fj < 4; ++fj)
          acc[fi][fj] = __builtin_amdgcn_mfma_f32_16x16x32_bf16(
              aF[fi], bF[fj], acc[fi][fj], 0, 0, 0);
    }

    if (bk == 3) {
      if (PASS == 0) {
        #pragma unroll
        for (int fj = 0; fj < 4; ++fj) {
          float cp = 0.0f;
          #pragma unroll
          for (int fi = 0; fi < 4; ++fi)
            #pragma unroll
            for (int i = 0; i < 4; ++i)
              cp += __expf(dist_L(acc[fi][fj][i]) - 40.0f);
          cp += __shfl_xor(cp, 16);
          cp += __shfl_xor(cp, 32);
          if (l4 == 0)
            atomicAdd(&colsum[mat * KC + tn0 + wn * 64 + fj * 16 + l15], cp);
        }
      } else {
        float lc[4];
        #pragma unroll
        for (int fj = 0; fj < 4; ++fj)
          lc[fj] = logC[mat * KC + tn0 + wn * 64 + fj * 16 + l15];

        if (mi < 2) {
          float* denP = rowAux + (size_t)mi * BH;
          #pragma unroll
          for (int fi = 0; fi < 4; ++fi) {
            float rp[4] = {0.f, 0.f, 0.f, 0.f};
            #pragma unroll
            for (int fj = 0; fj < 4; ++fj) {
              float G[4];
              #pragma unroll
              for (int i = 0; i < 4; ++i) {
                G[i] = dist_L(acc[fi][fj][i]) - lc[fj];
                rp[i] += __expf(G[i]);
              }
              if (mi == 0) {
                tvp[fi][fj][0] = pk2(G[0], G[1]);
                tvp[fi][fj][1] = pk2(G[2], G[3]);
              } else {
                unsigned o0 = tvp[fi][fj][0], o1 = tvp[fi][fj][1];
                tvp[fi][fj][0] = pk2(upk_lo(o0) + G[0], upk_hi(o0) + G[1]);
                tvp[fi][fj][1] = pk2(upk_lo(o1) + G[2], upk_hi(o1) + G[3]);
              }
            }
            #pragma unroll
            for (int i = 0; i < 4; ++i) {
              float v = rp[i];
              v += __shfl_xor(v, 1); v += __shfl_xor(v, 2);
              v += __shfl_xor(v, 4); v += __shfl_xor(v, 8);
              if (l15 == 0)
                atomicAdd(&denP[tm0 + wm * 64 + fi * 16 + l4 * 4 + i], v);
            }
          }
        } else {
          float* denZ = rowAux + (size_t)mi * BH;
          float* numZ = rowAux + (size_t)(mi + 2) * BH;
          #pragma unroll
          for (int fi = 0; fi < 4; ++fi)
            #pragma unroll
            for (int i = 0; i < 4; ++i) {
              float rd = 0.f, rn = 0.f;
              #pragma unroll
              for (int fj = 0; fj < 4; ++fj) {
                float G = dist_L(acc[fi][fj][i]) - lc[fj];
                float e = __expf(G);
                unsigned u = tvp[fi][fj][i >> 1];
                float tvv = (i & 1) ? upk_hi(u) : upk_lo(u);
                rd += e;
                rn += e * tvv;
              }
              rd += __shfl_xor(rd, 1); rd += __shfl_xor(rd, 2);
              rd += __shfl_xor(rd, 4); rd += __shfl_xor(rd, 8);
              rn += __shfl_xor(rn, 1); rn += __shfl_xor(rn, 2);
              rn += __shfl_xor(rn, 4); rn += __shfl_xor(rn, 8);
              if (l15 == 0) {
                int row = tm0 + wm * 64 + fi * 16 + l4 * 4 + i;
                atomicAdd(&denZ[row], rd);
                atomicAdd(&numZ[row], rn);
              }
            }
        }
      }
    }
    __syncthreads();
  }
}

extern "C" void kernel_launch(void* const* d_in, const int* in_sizes, int n_in,
                              void* d_out, int out_size, void* d_ws, size_t ws_size,
                              hipStream_t stream) {
  const float* z = (const float*)d_in[0];
  const float* p = (const float*)d_in[1];
  const float* c = (const float*)d_in[2];
  char* ws = (char*)d_ws;
  // layout: XA bf16 33.55MB | Cn 0.5MB | colsum 16KB | logC 16KB |
  //         rowAux 384KB | S u16 134.2MB (main path only)
  unsigned short* Xn = (unsigned short*)(ws);
  unsigned short* Cn = (unsigned short*)(ws + 33554432);
  float* colsum = (float*)(ws + 34078720);
  float* logC   = (float*)(ws + 34095104);
  float* rowAux = (float*)(ws + 34111488);   // 6*BH floats; rowv = first BH
  unsigned short* S = (unsigned short*)(ws + 34504704);
  float* out = (float*)d_out;

  const bool big = ws_size >= (size_t)34504704 + (size_t)4 * BH * KC * 2;

  norm_rows_kernel<<<16640, 256, 0, stream>>>(z, p, c, Xn, Cn);
  zero_kernel<<<384, 256, 0, stream>>>(colsum, rowAux, out);

  if (big) {
    gemm_s_kernel<<<1024, 256, 0, stream>>>(Xn, Cn, colsum, S);
    fin_logC_kernel<<<16, 256, 0, stream>>>(colsum, logC);
    pass2_mem_kernel<<<4096, 256, 0, stream>>>(S, logC, rowAux);
    fin_reduce_kernel<<<64, 256, 0, stream>>>(rowAux, out);
  } else {
    gemm_pass<0><<<1024, 256, 0, stream>>>(Xn, Cn, colsum, logC, rowAux);
    fin_logC_kernel<<<16, 256, 0, stream>>>(colsum, logC);
    gemm_pass<2><<<1024, 256, 0, stream>>>(Xn, Cn, colsum, logC, rowAux);
    fin_loss_kernel<<<64, 256, 0, stream>>>(rowAux, out);
  }
}